// Round 19
// baseline (746.607 us; speedup 1.0000x reference)
//
#include <hip/hip_runtime.h>
#include <hip/hip_bf16.h>
#include <math.h>

#define B 2
#define S 2048
#define E 128
#define H 8
#define HD 16
#define BH (B*H)

#define QT 64    // queries per block
#define KT 128   // key tile

__device__ __forceinline__ double dshfl_xor(double v, int lanemask) {
    long long u = __double_as_longlong(v);
    int lo = (int)(u & 0xffffffffLL);
    int hi = (int)(((unsigned long long)u) >> 32);
    lo = __shfl_xor(lo, lanemask);
    hi = __shfl_xor(hi, lanemask);
    long long r = (((long long)(unsigned)hi) << 32) | (unsigned)lo;
    return __longlong_as_double(r);
}

// FAITHFUL attention, f64 score path, F32 OUTPUT (the fixed knob: d_out is
// float32 — the reference returns f32; 18 rounds of bf16 writes were read
// as garbage by the checker's f32 reader).
//   split/merge d8h (e = d*8+h), scale 1/4, -1000 where src_mask==0
//   (masked scalar == 0 path).
__global__ __launch_bounds__(256) void fused_attn(
    const float* __restrict__ x,         // [B][S][E]
    const int* __restrict__ src_mask,    // [B][S]
    const int* __restrict__ masked_p,    // scalar
    const float* __restrict__ wq,
    const float* __restrict__ wk,
    const float* __restrict__ wv,
    float* __restrict__ out)             // [B][S][E] float32
{
    __shared__ float  wqs[E * HD];
    __shared__ float  wks[E * HD];
    __shared__ float  wvs[E * HD];
    __shared__ double Qs[QT * HD];
    __shared__ double Ks[KT * HD];
    __shared__ float  Vs[KT * HD];
    __shared__ float  Ms[KT];

    const int bh    = blockIdx.y;
    const int b     = bh >> 3;
    const int h     = bh & 7;
    const int qtile = blockIdx.x;
    const int tid   = threadIdx.x;
    const int masked = *masked_p;

    // stage head-columns (faithful split: col = d*8+h)
    #pragma unroll
    for (int r = 0; r < 8; ++r) {
        const int idx = tid + r * 256;          // 0..2047 = i*16+d
        const int i = idx >> 4, d = idx & 15;
        wqs[idx] = wq[i * E + d * 8 + h];
        wks[idx] = wk[i * E + d * 8 + h];
        wvs[idx] = wv[i * E + d * 8 + h];
    }
    __syncthreads();

    // Q tile in f64 (scale 0.25 folded): Qs[q*16+d]
    #pragma unroll
    for (int r = 0; r < 4; ++r) {
        const int idx = tid + r * 256;          // 0..1023 = q*16+d
        const int q = idx >> 4, d = idx & 15;
        const float* xr = x + (size_t)(b * S + qtile * QT + q) * E;
        double acc = 0.0;
        for (int i = 0; i < E; ++i)
            acc = fma((double)xr[i], (double)wqs[i * HD + d], acc);
        Qs[idx] = acc * 0.25;
    }
    __syncthreads();

    const int ql = tid >> 2;    // query within tile
    const int kk = tid & 3;     // key phase
    double qd[HD];
    #pragma unroll
    for (int d = 0; d < HD; ++d) qd[d] = Qs[ql * HD + d];

    double m = -INFINITY, l = 0.0;
    double acc[HD];
    #pragma unroll
    for (int d = 0; d < HD; ++d) acc[d] = 0.0;

    for (int kt = 0; kt < S / KT; ++kt) {
        __syncthreads();   // previous tile consumed

        // K (f64) / V (f32) tile
        #pragma unroll
        for (int r = 0; r < 8; ++r) {
            const int idx = tid + r * 256;       // 0..2047 = key*16+d
            const int key = idx >> 4, d = idx & 15;
            const float* xr = x + (size_t)(b * S + kt * KT + key) * E;
            double aK = 0.0, aV = 0.0;
            for (int i = 0; i < E; ++i) {
                const double xv = (double)xr[i];
                aK = fma(xv, (double)wks[i * HD + d], aK);
                aV = fma(xv, (double)wvs[i * HD + d], aV);
            }
            Ks[idx] = aK;
            Vs[idx] = (float)aV;
        }
        if (tid < KT) {
            float am = 0.f;
            if (!masked && src_mask[b * S + kt * KT + tid] == 0) am = -1000.f;
            Ms[tid] = am;
        }
        __syncthreads();

        for (int j = kk; j < KT; j += 4) {
            const double* kr = Ks + j * HD;
            double dot = 0.0;
            #pragma unroll
            for (int d = 0; d < HD; ++d) dot = fma(qd[d], kr[d], dot);
            dot += (double)Ms[j];

            const double mn    = fmax(m, dot);
            const double p     = exp(dot - mn);
            const double alpha = exp(m - mn);
            m = mn;
            l = l * alpha + p;

            const float* vr = Vs + j * HD;
            #pragma unroll
            for (int d = 0; d < HD; ++d)
                acc[d] = acc[d] * alpha + p * (double)vr[d];
        }
    }

    // merge the 4 key-phase lanes (f64)
    #pragma unroll
    for (int off = 1; off < 4; off <<= 1) {
        const double m2 = dshfl_xor(m, off);
        const double l2 = dshfl_xor(l, off);
        const double mn = fmax(m, m2);
        const double a1 = exp(m - mn);
        const double a2 = exp(m2 - mn);
        l = l * a1 + l2 * a2;
        #pragma unroll
        for (int d = 0; d < HD; ++d) {
            const double x2 = dshfl_xor(acc[d], off);
            acc[d] = acc[d] * a1 + x2 * a2;
        }
        m = mn;
    }

    if (kk == 0) {
        const int s = qtile * QT + ql;
        const double inv = 1.0 / l;
        // faithful merge: out[b][s][d*8+h], F32 write
        float* o = out + ((size_t)(b * S + s)) * E + h;
        #pragma unroll
        for (int d = 0; d < HD; ++d)
            o[d * H] = (float)(acc[d] * inv);
    }
}

extern "C" void kernel_launch(void* const* d_in, const int* in_sizes, int n_in,
                              void* d_out, int out_size, void* d_ws, size_t ws_size,
                              hipStream_t stream) {
    // Resolve by size signature; same-size buffers keep dict relative order:
    // x (B*S*E), src_mask then tgt_mask (B*S), masked (1), wq, wk, wv (E*E).
    int ix = 0, im0 = -1, isc = -1, iw[3] = {-1, -1, -1}, nw = 0;
    for (int i = 0; i < n_in; ++i) {
        const int sz = in_sizes[i];
        if (sz == B * S * E) ix = i;
        else if (sz == B * S) { if (im0 < 0) im0 = i; }
        else if (sz == E * E) { if (nw < 3) iw[nw++] = i; }
        else if (sz == 1 && isc < 0) isc = i;
    }
    if (im0 < 0) im0 = 1;
    if (isc < 0) isc = 3;
    if (nw < 3) { iw[0] = n_in - 3; iw[1] = n_in - 2; iw[2] = n_in - 1; }

    const float* x        = (const float*)d_in[ix];
    const int*   src_mask = (const int*)d_in[im0];
    const int*   masked_p = (const int*)d_in[isc];
    const float* wq       = (const float*)d_in[iw[0]];
    const float* wk       = (const float*)d_in[iw[1]];
    const float* wv       = (const float*)d_in[iw[2]];
    float*       out      = (float*)d_out;       // f32 output!

    fused_attn<<<dim3(S / QT, BH), 256, 0, stream>>>(
        x, src_mask, masked_p, wq, wk, wv, out);
}

// Round 20
// 140.496 us; speedup vs baseline: 5.3141x; 5.3141x over previous
//
#include <hip/hip_runtime.h>
#include <hip/hip_bf16.h>

#define B 2
#define S 2048
#define E 128
#define H 8
#define HD 16
#define BH (B*H)

#define RPB 8    // rows per block (qkv_proj)
#define QT 32    // queries per block (attn)
#define KT 128   // key tile
#define KPAD 20  // padded row stride (floats) for K/V/Q LDS tiles

// ---- Pass 0: QKV projection, 8 rows/block. Faithful d8h split. ----
// Q pre-scaled by 1/sqrt(16)=0.25. Layout: [bh][s][d] f32 in workspace.
__global__ __launch_bounds__(128) void qkv_proj(
    const float* __restrict__ x,
    const float* __restrict__ wq,
    const float* __restrict__ wk,
    const float* __restrict__ wv,
    float* __restrict__ Q, float* __restrict__ K, float* __restrict__ V)
{
    __shared__ float xs[RPB][E];
    const int row0 = blockIdx.x * RPB;
    const int c    = threadIdx.x;        // 0..127 output column
    #pragma unroll
    for (int rr = 0; rr < RPB; ++rr)
        xs[rr][c] = x[(size_t)(row0 + rr) * E + c];
    __syncthreads();

    float aq[RPB], ak[RPB], av[RPB];
    #pragma unroll
    for (int rr = 0; rr < RPB; ++rr) { aq[rr] = 0.f; ak[rr] = 0.f; av[rr] = 0.f; }

    for (int i = 0; i < E; ++i) {
        const float wqv = wq[i * E + c];
        const float wkv = wk[i * E + c];
        const float wvv = wv[i * E + c];
        #pragma unroll
        for (int rr = 0; rr < RPB; ++rr) {
            const float xv = xs[rr][i];
            aq[rr] = fmaf(xv, wqv, aq[rr]);
            ak[rr] = fmaf(xv, wkv, ak[rr]);
            av[rr] = fmaf(xv, wvv, av[rr]);
        }
    }

    const int h = c & 7, d = c >> 3;     // faithful split: col c = d*8+h
    #pragma unroll
    for (int rr = 0; rr < RPB; ++rr) {
        const int row = row0 + rr;
        const int b = row >> 11, s = row & 2047;
        const size_t off = (((size_t)(b * H + h)) * S + s) * HD + d;
        Q[off] = aq[rr] * 0.25f;
        K[off] = ak[rr];
        V[off] = av[rr];
    }
}

// ---- Pass 1: flash attention, f32. 32 queries x 8 key-lanes per block. ----
__global__ __launch_bounds__(256) void attn(
    const float* __restrict__ Q, const float* __restrict__ K,
    const float* __restrict__ V,
    const int* __restrict__ src_mask, const int* __restrict__ masked_p,
    float* __restrict__ out)
{
    __shared__ float Ks[KT * KPAD];     // padded: conflict-free 8-row b128 reads
    __shared__ float Vs[KT * KPAD];
    __shared__ float Qs[QT * KPAD];
    __shared__ float Ms[KT];

    const int bh    = blockIdx.y;
    const int b     = bh >> 3;
    const int h     = bh & 7;
    const int qtile = blockIdx.x;        // 0..63
    const int tid   = threadIdx.x;
    const int ql    = tid >> 3;          // 0..31
    const int kk    = tid & 7;           // key phase
    const int masked = *masked_p;

    // stage Q tile: 32 rows x 16 f32 = 128 float4 (padded rows)
    if (tid < 128) {
        const int row = tid >> 2, c4 = tid & 3;
        const float4 v = ((const float4*)(Q + ((size_t)bh * S + qtile * QT) * HD))[tid];
        ((float4*)(Qs + row * KPAD))[c4] = v;
    }
    __syncthreads();
    float4 q0, q1, q2, q3;
    {
        const float4* s4 = (const float4*)(Qs + ql * KPAD);
        q0 = s4[0]; q1 = s4[1]; q2 = s4[2]; q3 = s4[3];
    }

    float m = -INFINITY, l = 0.f;
    float acc[HD];
    #pragma unroll
    for (int d = 0; d < HD; ++d) acc[d] = 0.f;

    for (int kt = 0; kt < S / KT; ++kt) {
        __syncthreads();   // previous tile fully consumed
        {
            const float4* k4 = (const float4*)(K + ((size_t)bh * S + kt * KT) * HD);
            const float4* v4 = (const float4*)(V + ((size_t)bh * S + kt * KT) * HD);
            #pragma unroll
            for (int r = 0; r < 2; ++r) {
                const int idx4 = tid + r * 256;          // 0..511
                const int row = idx4 >> 2, c4 = idx4 & 3;
                ((float4*)(Ks + row * KPAD))[c4] = k4[idx4];
                ((float4*)(Vs + row * KPAD))[c4] = v4[idx4];
            }
            if (tid < KT) {
                float am = 0.f;
                if (!masked && src_mask[b * S + kt * KT + tid] == 0) am = -1000.f;
                Ms[tid] = am;
            }
        }
        __syncthreads();

        #pragma unroll 2
        for (int j = kk; j < KT; j += 8) {
            const float4* k4 = (const float4*)(Ks + j * KPAD);
            const float4 ka = k4[0], kb = k4[1], kc = k4[2], kd = k4[3];
            float dot;
            dot = q0.x * ka.x;
            dot = fmaf(q0.y, ka.y, dot);
            dot = fmaf(q0.z, ka.z, dot);
            dot = fmaf(q0.w, ka.w, dot);
            dot = fmaf(q1.x, kb.x, dot);
            dot = fmaf(q1.y, kb.y, dot);
            dot = fmaf(q1.z, kb.z, dot);
            dot = fmaf(q1.w, kb.w, dot);
            dot = fmaf(q2.x, kc.x, dot);
            dot = fmaf(q2.y, kc.y, dot);
            dot = fmaf(q2.z, kc.z, dot);
            dot = fmaf(q2.w, kc.w, dot);
            dot = fmaf(q3.x, kd.x, dot);
            dot = fmaf(q3.y, kd.y, dot);
            dot = fmaf(q3.z, kd.z, dot);
            dot = fmaf(q3.w, kd.w, dot);

            const float sc = dot + Ms[j];
            const float mn = fmaxf(m, sc);
            const float p     = __expf(sc - mn);
            const float alpha = __expf(m - mn);
            m = mn;
            l = fmaf(l, alpha, p);

            const float4* v4 = (const float4*)(Vs + j * KPAD);
            const float4 va = v4[0], vb = v4[1], vc = v4[2], vd = v4[3];
            acc[0]  = fmaf(acc[0],  alpha, p * va.x);
            acc[1]  = fmaf(acc[1],  alpha, p * va.y);
            acc[2]  = fmaf(acc[2],  alpha, p * va.z);
            acc[3]  = fmaf(acc[3],  alpha, p * va.w);
            acc[4]  = fmaf(acc[4],  alpha, p * vb.x);
            acc[5]  = fmaf(acc[5],  alpha, p * vb.y);
            acc[6]  = fmaf(acc[6],  alpha, p * vb.z);
            acc[7]  = fmaf(acc[7],  alpha, p * vb.w);
            acc[8]  = fmaf(acc[8],  alpha, p * vc.x);
            acc[9]  = fmaf(acc[9],  alpha, p * vc.y);
            acc[10] = fmaf(acc[10], alpha, p * vc.z);
            acc[11] = fmaf(acc[11], alpha, p * vc.w);
            acc[12] = fmaf(acc[12], alpha, p * vd.x);
            acc[13] = fmaf(acc[13], alpha, p * vd.y);
            acc[14] = fmaf(acc[14], alpha, p * vd.z);
            acc[15] = fmaf(acc[15], alpha, p * vd.w);
        }
    }

    // merge the 8 key-phase lanes (consecutive lanes, same wave)
    #pragma unroll
    for (int off = 1; off < 8; off <<= 1) {
        const float m2 = __shfl_xor(m, off);
        const float l2 = __shfl_xor(l, off);
        const float mn = fmaxf(m, m2);
        const float a1 = __expf(m - mn);
        const float a2 = __expf(m2 - mn);
        l = l * a1 + l2 * a2;
        #pragma unroll
        for (int d = 0; d < HD; ++d) {
            const float x2 = __shfl_xor(acc[d], off);
            acc[d] = acc[d] * a1 + x2 * a2;
        }
        m = mn;
    }

    if (kk == 0) {
        const int s = qtile * QT + ql;
        const float inv = 1.f / l;
        // faithful merge: out[b][s][d*8+h], f32
        float* o = out + ((size_t)(b * S + s)) * E + h;
        #pragma unroll
        for (int d = 0; d < HD; ++d)
            o[d * H] = acc[d] * inv;
    }
}

extern "C" void kernel_launch(void* const* d_in, const int* in_sizes, int n_in,
                              void* d_out, int out_size, void* d_ws, size_t ws_size,
                              hipStream_t stream) {
    // size-signature resolution; same-size buffers keep dict relative order
    int ix = 0, im0 = -1, isc = -1, iw[3] = {-1, -1, -1}, nw = 0;
    for (int i = 0; i < n_in; ++i) {
        const int sz = in_sizes[i];
        if (sz == B * S * E) ix = i;
        else if (sz == B * S) { if (im0 < 0) im0 = i; }
        else if (sz == E * E) { if (nw < 3) iw[nw++] = i; }
        else if (sz == 1 && isc < 0) isc = i;
    }
    if (im0 < 0) im0 = 1;
    if (isc < 0) isc = 3;
    if (nw < 3) { iw[0] = n_in - 3; iw[1] = n_in - 2; iw[2] = n_in - 1; }

    const float* x        = (const float*)d_in[ix];
    const int*   src_mask = (const int*)d_in[im0];
    const int*   masked_p = (const int*)d_in[isc];
    const float* wq       = (const float*)d_in[iw[0]];
    const float* wk       = (const float*)d_in[iw[1]];
    const float* wv       = (const float*)d_in[iw[2]];
    float*       out      = (float*)d_out;

    float* Qw = (float*)d_ws;                    // [BH][S][HD] each, 2 MB
    float* Kw = Qw + (size_t)BH * S * HD;
    float* Vw = Kw + (size_t)BH * S * HD;

    qkv_proj<<<B * S / RPB, 128, 0, stream>>>(x, wq, wk, wv, Qw, Kw, Vw);
    attn<<<dim3(S / QT, BH), 256, 0, stream>>>(Qw, Kw, Vw, src_mask, masked_p, out);
}

// Round 21
// 126.259 us; speedup vs baseline: 5.9133x; 1.1128x over previous
//
#include <hip/hip_runtime.h>
#include <hip/hip_bf16.h>

#define B 2
#define S 2048
#define E 128
#define H 8
#define HD 16
#define BH (B*H)

#define RPB 8    // rows per block (qkv_proj)
#define QT 32    // queries per block (attn)
#define KT 128   // key tile
#define KPAD 20  // padded row stride (floats) for K/V LDS tiles

// ---- Pass 0: QKV projection, 8 rows/block. Faithful d8h split. ----
__global__ __launch_bounds__(128) void qkv_proj(
    const float* __restrict__ x,
    const float* __restrict__ wq,
    const float* __restrict__ wk,
    const float* __restrict__ wv,
    float* __restrict__ Q, float* __restrict__ K, float* __restrict__ V)
{
    __shared__ float xs[RPB][E];
    const int row0 = blockIdx.x * RPB;
    const int c    = threadIdx.x;        // 0..127 output column
    #pragma unroll
    for (int rr = 0; rr < RPB; ++rr)
        xs[rr][c] = x[(size_t)(row0 + rr) * E + c];
    __syncthreads();

    float aq[RPB], ak[RPB], av[RPB];
    #pragma unroll
    for (int rr = 0; rr < RPB; ++rr) { aq[rr] = 0.f; ak[rr] = 0.f; av[rr] = 0.f; }

    for (int i = 0; i < E; ++i) {
        const float wqv = wq[i * E + c];
        const float wkv = wk[i * E + c];
        const float wvv = wv[i * E + c];
        #pragma unroll
        for (int rr = 0; rr < RPB; ++rr) {
            const float xv = xs[rr][i];
            aq[rr] = fmaf(xv, wqv, aq[rr]);
            ak[rr] = fmaf(xv, wkv, ak[rr]);
            av[rr] = fmaf(xv, wvv, av[rr]);
        }
    }

    const int h = c & 7, d = c >> 3;     // faithful split: col c = d*8+h
    #pragma unroll
    for (int rr = 0; rr < RPB; ++rr) {
        const int row = row0 + rr;
        const int b = row >> 11, s = row & 2047;
        const size_t off = (((size_t)(b * H + h)) * S + s) * HD + d;
        Q[off] = aq[rr] * 0.25f;
        K[off] = ak[rr];
        V[off] = av[rr];
    }
}

// ---- Pass 1: flash attention, f32, TILE-DEFERRED softmax. ----
// 32 queries x 8 key-lanes per block. Per tile: 16 register scores/lane,
// tile-max, at-most-one acc rescale, then 1 exp + 16 FMA per key.
__global__ __launch_bounds__(256) void attn(
    const float* __restrict__ Q, const float* __restrict__ K,
    const float* __restrict__ V,
    const int* __restrict__ src_mask, const int* __restrict__ masked_p,
    float* __restrict__ out)
{
    __shared__ float Ks[KT * KPAD];
    __shared__ float Vs[KT * KPAD];
    __shared__ float Ms[KT];

    const int bh    = blockIdx.y;
    const int b     = bh >> 3;
    const int h     = bh & 7;
    const int qtile = blockIdx.x;        // 0..63
    const int tid   = threadIdx.x;
    const int ql    = tid >> 3;          // 0..31 query within tile
    const int kk    = tid & 7;           // key phase
    const int masked = *masked_p;

    // Q row straight from global (8 lanes share one row -> L1 broadcast)
    float4 q0, q1, q2, q3;
    {
        const float4* qg = (const float4*)(Q + ((size_t)bh * S + qtile * QT + ql) * HD);
        q0 = qg[0]; q1 = qg[1]; q2 = qg[2]; q3 = qg[3];
    }

    float m = -INFINITY, l = 0.f;
    float acc[HD];
    #pragma unroll
    for (int d = 0; d < HD; ++d) acc[d] = 0.f;

    for (int kt = 0; kt < S / KT; ++kt) {
        __syncthreads();   // previous tile fully consumed
        {
            const float4* k4 = (const float4*)(K + ((size_t)bh * S + kt * KT) * HD);
            const float4* v4 = (const float4*)(V + ((size_t)bh * S + kt * KT) * HD);
            #pragma unroll
            for (int r = 0; r < 2; ++r) {
                const int idx4 = tid + r * 256;          // 0..511
                const int row = idx4 >> 2, c4 = idx4 & 3;
                ((float4*)(Ks + row * KPAD))[c4] = k4[idx4];
                ((float4*)(Vs + row * KPAD))[c4] = v4[idx4];
            }
            if (tid < KT) {
                float am = 0.f;
                if (!masked && src_mask[b * S + kt * KT + tid] == 0) am = -1000.f;
                Ms[tid] = am;
            }
        }
        __syncthreads();

        // phase 1: 16 independent scores into registers
        float s[16];
        #pragma unroll
        for (int jj = 0; jj < 16; ++jj) {
            const int j = kk + jj * 8;
            const float4* k4 = (const float4*)(Ks + j * KPAD);
            const float4 ka = k4[0], kb = k4[1], kc = k4[2], kd = k4[3];
            float dot;
            dot = q0.x * ka.x;
            dot = fmaf(q0.y, ka.y, dot);
            dot = fmaf(q0.z, ka.z, dot);
            dot = fmaf(q0.w, ka.w, dot);
            dot = fmaf(q1.x, kb.x, dot);
            dot = fmaf(q1.y, kb.y, dot);
            dot = fmaf(q1.z, kb.z, dot);
            dot = fmaf(q1.w, kb.w, dot);
            dot = fmaf(q2.x, kc.x, dot);
            dot = fmaf(q2.y, kc.y, dot);
            dot = fmaf(q2.z, kc.z, dot);
            dot = fmaf(q2.w, kc.w, dot);
            dot = fmaf(q3.x, kd.x, dot);
            dot = fmaf(q3.y, kd.y, dot);
            dot = fmaf(q3.z, kd.z, dot);
            dot = fmaf(q3.w, kd.w, dot);
            s[jj] = dot + Ms[j];
        }

        // phase 2: tile max, at-most-one rescale
        float tm = s[0];
        #pragma unroll
        for (int jj = 1; jj < 16; ++jj) tm = fmaxf(tm, s[jj]);
        if (tm > m) {
            const float alpha = __expf(m - tm);   // exp(-inf)=0 zeroes acc at kt=0
            l *= alpha;
            #pragma unroll
            for (int d = 0; d < HD; ++d) acc[d] *= alpha;
            m = tm;
        }

        // phase 3: one exp + 16 FMA per key
        #pragma unroll
        for (int jj = 0; jj < 16; ++jj) {
            const int j = kk + jj * 8;
            const float p = __expf(s[jj] - m);
            l += p;
            const float4* v4 = (const float4*)(Vs + j * KPAD);
            const float4 va = v4[0], vb = v4[1], vc = v4[2], vd = v4[3];
            acc[0]  = fmaf(p, va.x, acc[0]);
            acc[1]  = fmaf(p, va.y, acc[1]);
            acc[2]  = fmaf(p, va.z, acc[2]);
            acc[3]  = fmaf(p, va.w, acc[3]);
            acc[4]  = fmaf(p, vb.x, acc[4]);
            acc[5]  = fmaf(p, vb.y, acc[5]);
            acc[6]  = fmaf(p, vb.z, acc[6]);
            acc[7]  = fmaf(p, vb.w, acc[7]);
            acc[8]  = fmaf(p, vc.x, acc[8]);
            acc[9]  = fmaf(p, vc.y, acc[9]);
            acc[10] = fmaf(p, vc.z, acc[10]);
            acc[11] = fmaf(p, vc.w, acc[11]);
            acc[12] = fmaf(p, vd.x, acc[12]);
            acc[13] = fmaf(p, vd.y, acc[13]);
            acc[14] = fmaf(p, vd.z, acc[14]);
            acc[15] = fmaf(p, vd.w, acc[15]);
        }
    }

    // merge the 8 key-phase lanes (consecutive lanes, same wave)
    #pragma unroll
    for (int off = 1; off < 8; off <<= 1) {
        const float m2 = __shfl_xor(m, off);
        const float l2 = __shfl_xor(l, off);
        const float mn = fmaxf(m, m2);
        const float a1 = __expf(m - mn);
        const float a2 = __expf(m2 - mn);
        l = l * a1 + l2 * a2;
        #pragma unroll
        for (int d = 0; d < HD; ++d) {
            const float x2 = __shfl_xor(acc[d], off);
            acc[d] = acc[d] * a1 + x2 * a2;
        }
        m = mn;
    }

    if (kk == 0) {
        const int s = qtile * QT + ql;
        const float inv = 1.f / l;
        // faithful merge: out[b][s][d*8+h], f32
        float* o = out + ((size_t)(b * S + s)) * E + h;
        #pragma unroll
        for (int d = 0; d < HD; ++d)
            o[d * H] = acc[d] * inv;
    }
}

extern "C" void kernel_launch(void* const* d_in, const int* in_sizes, int n_in,
                              void* d_out, int out_size, void* d_ws, size_t ws_size,
                              hipStream_t stream) {
    // size-signature resolution; same-size buffers keep dict relative order
    int ix = 0, im0 = -1, isc = -1, iw[3] = {-1, -1, -1}, nw = 0;
    for (int i = 0; i < n_in; ++i) {
        const int sz = in_sizes[i];
        if (sz == B * S * E) ix = i;
        else if (sz == B * S) { if (im0 < 0) im0 = i; }
        else if (sz == E * E) { if (nw < 3) iw[nw++] = i; }
        else if (sz == 1 && isc < 0) isc = i;
    }
    if (im0 < 0) im0 = 1;
    if (isc < 0) isc = 3;
    if (nw < 3) { iw[0] = n_in - 3; iw[1] = n_in - 2; iw[2] = n_in - 1; }

    const float* x        = (const float*)d_in[ix];
    const int*   src_mask = (const int*)d_in[im0];
    const int*   masked_p = (const int*)d_in[isc];
    const float* wq       = (const float*)d_in[iw[0]];
    const float* wk       = (const float*)d_in[iw[1]];
    const float* wv       = (const float*)d_in[iw[2]];
    float*       out      = (float*)d_out;

    float* Qw = (float*)d_ws;                    // [BH][S][HD] each, 2 MB
    float* Kw = Qw + (size_t)BH * S * HD;
    float* Vw = Kw + (size_t)BH * S * HD;

    qkv_proj<<<B * S / RPB, 128, 0, stream>>>(x, wq, wk, wv, Qw, Kw, Vw);
    attn<<<dim3(S / QT, BH), 256, 0, stream>>>(Qw, Kw, Vw, src_mask, masked_p, out);
}